// Round 1
// baseline (544.995 us; speedup 1.0000x reference)
//
#include <hip/hip_runtime.h>
#include <hip/hip_bf16.h>
#include <math.h>

#define BB   64
#define NP1  577
#define DD   768
#define NNP  576      // N patches
#define DENS 288      // kept high-attn tokens
#define SS   288      // skip tokens (graph nodes per batch)
#define NN   (BB*SS)  // 18432 total nodes
#define KNN  2
#define NPAIR (NN*KNN)   // 36864
#define NE    (2*NPAIR)  // 73728 directed candidate edges
#define NEW   (NE/32)    // 2304 mask words
#define GG   144
#define TOK  (1+DENS+GG) // 433

// ---------------------------------------------------------------- K1: sort
// stable descending argsort of cls_attn per batch (ties -> lower index first)
__global__ __launch_bounds__(256) void k_sort(const float* __restrict__ ca,
                                              int* __restrict__ order,
                                              float* __restrict__ ca_sorted) {
    __shared__ float v[1024];
    __shared__ int   ix[1024];
    const int b = blockIdx.x;
    for (int i = threadIdx.x; i < 1024; i += 256) {
        if (i < NNP) { v[i] = ca[b*NNP + i]; }
        else         { v[i] = -INFINITY; }
        ix[i] = i;
    }
    __syncthreads();
    for (int k = 2; k <= 1024; k <<= 1) {
        for (int j = k >> 1; j > 0; j >>= 1) {
            for (int t = threadIdx.x; t < 1024; t += 256) {
                int p = t ^ j;
                if (p > t) {
                    float va = v[t], vb = v[p];
                    int   ia = ix[t], ib = ix[p];
                    // lpt: element at p should come BEFORE element at t
                    bool lpt = (vb > va) || (vb == va && ib < ia);
                    bool up  = ((t & k) == 0);
                    if (lpt == up) { v[t] = vb; v[p] = va; ix[t] = ib; ix[p] = ia; }
                }
            }
            __syncthreads();
        }
    }
    for (int i = threadIdx.x; i < NNP; i += 256) {
        order[b*NNP + i]     = ix[i];
        ca_sorted[b*NNP + i] = v[i];
    }
}

// ---------------------------------------------------------------- K2: kNN top-2
__global__ __launch_bounds__(320) void k_knn(const float* __restrict__ ex,
                                             const int* __restrict__ order,
                                             int* __restrict__ nbr) {
    __shared__ float cn[SS][16];   // 18 KB
    const int b = blockIdx.x, t = threadIdx.x;
    if (t < SS) {
        int src = order[b*NNP + DENS + t];
        const float* row = ex + ((size_t)b*NP1 + 1 + src) * 16;
        float vv[16]; float ss = 0.f;
        #pragma unroll
        for (int e = 0; e < 16; e++) { vv[e] = row[e]; ss += vv[e]*vv[e]; }
        float inv = 1.0f / fmaxf(sqrtf(ss), 1e-12f);
        #pragma unroll
        for (int e = 0; e < 16; e++) cn[t][e] = vv[e]*inv;
    }
    __syncthreads();
    if (t < SS) {
        float my[16];
        #pragma unroll
        for (int e = 0; e < 16; e++) my[e] = cn[t][e];
        float v1 = -3.f, v2 = -3.f; int i1 = -1, i2 = -1;
        for (int j = 0; j < SS; j++) {
            if (j == t) continue;                 // diag = -2 never wins
            float s = 0.f;
            #pragma unroll
            for (int e = 0; e < 16; e++) s = fmaf(my[e], cn[j][e], s);
            if (s > v1)      { v2 = v1; i2 = i1; v1 = s; i1 = j; }
            else if (s > v2) { v2 = s;  i2 = j; }
        }
        nbr[(b*SS + t)*2 + 0] = i1;
        nbr[(b*SS + t)*2 + 1] = i2;
    }
}

// ---------------------------------------------------------------- K3: pairs + dedup
__global__ __launch_bounds__(256) void k_pairs(const int* __restrict__ nbr,
                                               unsigned* __restrict__ edges,
                                               unsigned char* __restrict__ ev0) {
    int idx = blockIdx.x*256 + threadIdx.x;
    if (idx >= NPAIR) return;
    int j  = idx & 1;
    int ns = idx >> 1;          // global node id (b*SS+n)
    int b  = ns / SS;
    int n  = ns - b*SS;
    int p  = nbr[ns*2 + j];     // within-batch neighbor index
    int pg = b*SS + p;
    bool mutual = (nbr[pg*2+0] == n) || (nbr[pg*2+1] == n);
    unsigned char pv = (!mutual || (n < p)) ? 1 : 0;
    unsigned gn = (unsigned)ns, gp = (unsigned)pg;
    edges[2*idx + 0] = (gp << 16) | gn;   // p -> n
    edges[2*idx + 1] = (gn << 16) | gp;   // n -> p
    ev0[2*idx + 0] = pv;
    ev0[2*idx + 1] = pv;
}

// ---------------------------------------------------------------- K4: fixpoint + CSR
__global__ __launch_bounds__(1024) void k_fixpoint(const unsigned* __restrict__ edges,
                                                   const unsigned char* __restrict__ ev0,
                                                   int* __restrict__ nd,
                                                   unsigned* __restrict__ rowptr,
                                                   unsigned* __restrict__ cursor,
                                                   unsigned* __restrict__ col) {
    __shared__ unsigned degp[NN/2];  // packed u16 degrees, 36864 B
    __shared__ unsigned mask[NEW];   // 9216 B
    __shared__ unsigned red[1024];   // 4096 B
    const int t = threadIdx.x;

    for (int w = t; w < NEW; w += 1024) {
        unsigned m = 0;
        #pragma unroll 4
        for (int i = 0; i < 32; i++) m |= (unsigned)(ev0[w*32 + i] & 1) << i;
        mask[w] = m;
    }
    __syncthreads();

    int prev = -1;
    while (true) {
        for (int i = t; i < NN/2; i += 1024) degp[i] = 0;
        __syncthreads();
        for (int w = t; w < NEW; w += 1024) {
            unsigned m = mask[w];
            while (m) {
                int i = __ffs(m) - 1; m &= m - 1;
                unsigned e = edges[w*32 + i];
                unsigned dst = e & 0xFFFFu;
                atomicAdd(&degp[dst >> 1], 1u << ((dst & 1)*16));
            }
        }
        __syncthreads();
        unsigned cnt = 0;
        for (int w = t; w < NEW; w += 1024) {
            unsigned m = mask[w], nm = m;
            while (m) {
                int i = __ffs(m) - 1; m &= m - 1;
                unsigned e = edges[w*32 + i];
                unsigned dst = e & 0xFFFFu, src = e >> 16;
                unsigned dd = (degp[dst >> 1] >> ((dst & 1)*16)) & 0xFFFFu;
                unsigned ds = (degp[src >> 1] >> ((src & 1)*16)) & 0xFFFFu;
                if (!(dd > ds)) nm &= ~(1u << i);
            }
            mask[w] = nm;
            cnt += (unsigned)__popc(nm);
        }
        red[t] = cnt;
        __syncthreads();
        for (int o = 512; o > 0; o >>= 1) {
            if (t < o) red[t] += red[t + o];
            __syncthreads();
        }
        int total = (int)red[0];
        __syncthreads();
        if (total == prev) break;
        prev = total;
    }

    // out-degree (+1) -> nd
    for (int i = t; i < NN/2; i += 1024) degp[i] = 0;
    __syncthreads();
    for (int w = t; w < NEW; w += 1024) {
        unsigned m = mask[w];
        while (m) {
            int i = __ffs(m) - 1; m &= m - 1;
            unsigned src = edges[w*32 + i] >> 16;
            atomicAdd(&degp[src >> 1], 1u << ((src & 1)*16));
        }
    }
    __syncthreads();
    for (int g = t; g < NN; g += 1024)
        nd[g] = (int)((degp[g >> 1] >> ((g & 1)*16)) & 0xFFFFu) + 1;
    __syncthreads();

    // in-degree for CSR
    for (int i = t; i < NN/2; i += 1024) degp[i] = 0;
    __syncthreads();
    for (int w = t; w < NEW; w += 1024) {
        unsigned m = mask[w];
        while (m) {
            int i = __ffs(m) - 1; m &= m - 1;
            unsigned dst = edges[w*32 + i] & 0xFFFFu;
            atomicAdd(&degp[dst >> 1], 1u << ((dst & 1)*16));
        }
    }
    __syncthreads();

    // exclusive scan of in-degrees (18 nodes per thread, 1024 chunks)
    unsigned csum = 0;
    {
        int base = t*18;
        for (int q = 0; q < 18; q++) {
            int g = base + q;
            csum += (degp[g >> 1] >> ((g & 1)*16)) & 0xFFFFu;
        }
    }
    red[t] = csum;
    __syncthreads();
    for (int o = 1; o < 1024; o <<= 1) {
        unsigned v2 = (t >= o) ? red[t - o] : 0u;
        __syncthreads();
        red[t] += v2;
        __syncthreads();
    }
    unsigned run = red[t] - csum;  // exclusive prefix of my chunk
    {
        int base = t*18;
        for (int q = 0; q < 18; q++) {
            int g = base + q;
            rowptr[g] = run;
            cursor[g] = run;
            run += (degp[g >> 1] >> ((g & 1)*16)) & 0xFFFFu;
        }
        if (t == 1023) rowptr[NN] = run;
    }
    __syncthreads();

    // scatter CSR columns
    for (int w = t; w < NEW; w += 1024) {
        unsigned m = mask[w];
        while (m) {
            int i = __ffs(m) - 1; m &= m - 1;
            unsigned e = edges[w*32 + i];
            unsigned dst = e & 0xFFFFu, src = e >> 16;
            unsigned pos = atomicAdd(&cursor[dst], 1u);
            col[pos] = src;
        }
    }
}

// ---------------------------------------------------------------- K5: top-G by degree
__global__ __launch_bounds__(320) void k_topg(const int* __restrict__ nd,
                                              int* __restrict__ gidx) {
    __shared__ int snd[SS];
    const int b = blockIdx.x, t = threadIdx.x;
    if (t < SS) snd[t] = nd[b*SS + t];
    __syncthreads();
    if (t < SS) {
        int mine = snd[t];
        int rank = 0;
        for (int m = 0; m < SS; m++) {
            int v = snd[m];
            rank += (v > mine) || (v == mine && m < t);
        }
        if (rank < GG) gidx[b*GG + rank] = t;
    }
}

// ---------------------------------------------------------------- K6: tokens
__global__ __launch_bounds__(256) void k_tokens(const float* __restrict__ x,
                                                const int* __restrict__ order,
                                                const int* __restrict__ gidx,
                                                const unsigned* __restrict__ rowptr,
                                                const unsigned* __restrict__ col,
                                                float* __restrict__ out) {
    const int wid  = threadIdx.x >> 6;
    const int lane = threadIdx.x & 63;
    int row = blockIdx.x*4 + wid;
    if (row >= BB*TOK) return;
    int b  = row / TOK;
    int tk = row - b*TOK;
    float4* __restrict__ orow = (float4*)(out + (size_t)row*DD);

    if (tk <= DENS) {
        // cls token (tk==0) or kept patch
        int srcrow = (tk == 0) ? (b*NP1) : (b*NP1 + 1 + order[b*NNP + (tk-1)]);
        const float4* s4 = (const float4*)(x + (size_t)srcrow*DD);
        #pragma unroll
        for (int q = 0; q < 3; q++) orow[lane + q*64] = s4[lane + q*64];
    } else {
        int r = tk - 1 - DENS;
        int n = gidx[b*GG + r];
        int g = b*SS + n;
        float4 acc0 = make_float4(0,0,0,0), acc1 = acc0, acc2 = acc0;
        unsigned e0 = rowptr[g], e1 = rowptr[g+1];
        for (unsigned e = e0; e < e1; e++) {
            int sg = (int)col[e];
            int sn = sg - b*SS;
            int so = order[b*NNP + DENS + sn];
            const float4* s4 = (const float4*)(x + ((size_t)b*NP1 + 1 + so)*DD);
            float4 a = s4[lane], bq = s4[lane + 64], c = s4[lane + 128];
            acc0.x += a.x;  acc0.y += a.y;  acc0.z += a.z;  acc0.w += a.w;
            acc1.x += bq.x; acc1.y += bq.y; acc1.z += bq.z; acc1.w += bq.w;
            acc2.x += c.x;  acc2.y += c.y;  acc2.z += c.z;  acc2.w += c.w;
        }
        int so = order[b*NNP + DENS + n];
        const float4* s4 = (const float4*)(x + ((size_t)b*NP1 + 1 + so)*DD);
        float4 a = s4[lane], bq = s4[lane + 64], c = s4[lane + 128];
        acc0.x += a.x;  acc0.y += a.y;  acc0.z += a.z;  acc0.w += a.w;
        acc1.x += bq.x; acc1.y += bq.y; acc1.z += bq.z; acc1.w += bq.w;
        acc2.x += c.x;  acc2.y += c.y;  acc2.z += c.z;  acc2.w += c.w;
        orow[lane]       = acc0;
        orow[lane + 64]  = acc1;
        orow[lane + 128] = acc2;
    }
}

// ---------------------------------------------------------------- K7: attn
__global__ __launch_bounds__(256) void k_attn(const float* __restrict__ ca_sorted,
                                              const int* __restrict__ gidx,
                                              float* __restrict__ out_attn) {
    int idx = blockIdx.x*256 + threadIdx.x;
    if (idx >= BB*(DENS+GG)) return;
    int b = idx / (DENS+GG);
    int i = idx - b*(DENS+GG);
    float v;
    if (i < DENS) v = ca_sorted[b*NNP + i];
    else          v = ca_sorted[b*NNP + DENS + gidx[b*GG + (i - DENS)]];
    out_attn[idx] = v;
}

// ---------------------------------------------------------------- launch
extern "C" void kernel_launch(void* const* d_in, const int* in_sizes, int n_in,
                              void* d_out, int out_size, void* d_ws, size_t ws_size,
                              hipStream_t stream) {
    const float* x  = (const float*)d_in[0];
    const float* ca = (const float*)d_in[1];
    const float* ex = (const float*)d_in[2];
    float* out = (float*)d_out;

    char* w = (char*)d_ws;
    int*      order     = (int*)w;           w += (size_t)BB*NNP*4;
    float*    ca_sorted = (float*)w;         w += (size_t)BB*NNP*4;
    int*      nbr       = (int*)w;           w += (size_t)NN*2*4;
    unsigned* edges     = (unsigned*)w;      w += (size_t)NE*4;
    unsigned char* ev0  = (unsigned char*)w; w += (size_t)NE;
    int*      nd        = (int*)w;           w += (size_t)NN*4;
    unsigned* rowptr    = (unsigned*)w;      w += (size_t)(NN+2)*4;
    unsigned* cursor    = (unsigned*)w;      w += (size_t)NN*4;
    unsigned* col       = (unsigned*)w;      w += (size_t)NE*4;
    int*      gidx      = (int*)w;           w += (size_t)BB*GG*4;

    k_sort<<<BB, 256, 0, stream>>>(ca, order, ca_sorted);
    k_knn<<<BB, 320, 0, stream>>>(ex, order, nbr);
    k_pairs<<<(NPAIR + 255)/256, 256, 0, stream>>>(nbr, edges, ev0);
    k_fixpoint<<<1, 1024, 0, stream>>>(edges, ev0, nd, rowptr, cursor, col);
    k_topg<<<BB, 320, 0, stream>>>(nd, gidx);
    k_tokens<<<(BB*TOK + 3)/4, 256, 0, stream>>>(x, order, gidx, rowptr, col, out);
    k_attn<<<(BB*(DENS+GG) + 255)/256, 256, 0, stream>>>(ca_sorted, gidx,
                                                         out + (size_t)BB*TOK*DD);
}

// Round 2
// 292.274 us; speedup vs baseline: 1.8647x; 1.8647x over previous
//
#include <hip/hip_runtime.h>
#include <hip/hip_bf16.h>
#include <math.h>

#define BB   64
#define NP1  577
#define DD   768
#define NNP  576      // N patches
#define DENS 288      // kept high-attn tokens
#define SS   288      // skip tokens (graph nodes per batch)
#define KNN  2
#define EPB  (SS*KNN*2)   // 1152 directed candidate edges per batch
#define GG   144
#define TOK  (1+DENS+GG)  // 433
#define ATT  (DENS+GG)    // 432

// ---------------------------------------------------------------- K1: sort
// stable descending argsort of cls_attn per batch (ties -> lower index first)
__global__ __launch_bounds__(256) void k_sort(const float* __restrict__ ca,
                                              int* __restrict__ order,
                                              float* __restrict__ ca_sorted) {
    __shared__ float v[1024];
    __shared__ int   ix[1024];
    const int b = blockIdx.x;
    for (int i = threadIdx.x; i < 1024; i += 256) {
        if (i < NNP) { v[i] = ca[b*NNP + i]; }
        else         { v[i] = -INFINITY; }
        ix[i] = i;
    }
    __syncthreads();
    for (int k = 2; k <= 1024; k <<= 1) {
        for (int j = k >> 1; j > 0; j >>= 1) {
            for (int t = threadIdx.x; t < 1024; t += 256) {
                int p = t ^ j;
                if (p > t) {
                    float va = v[t], vb = v[p];
                    int   ia = ix[t], ib = ix[p];
                    bool lpt = (vb > va) || (vb == va && ib < ia);
                    bool up  = ((t & k) == 0);
                    if (lpt == up) { v[t] = vb; v[p] = va; ix[t] = ib; ix[p] = ia; }
                }
            }
            __syncthreads();
        }
    }
    for (int i = threadIdx.x; i < NNP; i += 256) {
        order[b*NNP + i]     = ix[i];
        ca_sorted[b*NNP + i] = v[i];
    }
}

// ---------------------------------------------------------------- K2: fused graph
// per-batch: knn -> pairs+dedup -> directional-degree fixpoint -> out-degree
// -> top-G by degree -> CSR (global x-row ids) -> attn output
__global__ __launch_bounds__(320) void k_graph(const float* __restrict__ ex,
                                               const int* __restrict__ order,
                                               const float* __restrict__ ca_sorted,
                                               unsigned* __restrict__ rowptr,  // BB*(SS+1)
                                               unsigned* __restrict__ col,     // BB*EPB
                                               int* __restrict__ selnode,      // BB*GG
                                               int* __restrict__ selrow,       // BB*GG
                                               float* __restrict__ out_attn) {
    __shared__ float    cn[SS][16];      // normalized expert features
    __shared__ int      nbrs[SS][2];
    __shared__ unsigned edge[EPB];       // (src<<16)|dst, batch-local ids
    __shared__ unsigned char act[EPB];
    __shared__ unsigned deg[SS];
    __shared__ int      ndv[SS];
    __shared__ unsigned scan[320];
    __shared__ int      srow[SS];        // global x row per node
    __shared__ int      gsel[GG];
    __shared__ unsigned tot;
    const int b = blockIdx.x, t = threadIdx.x;

    // ---- load + normalize expert features
    if (t < SS) {
        int src = order[b*NNP + DENS + t];
        srow[t] = b*NP1 + 1 + src;
        const float* row = ex + ((size_t)b*NP1 + 1 + src) * 16;
        float vv[16]; float ssum = 0.f;
        #pragma unroll
        for (int e = 0; e < 16; e++) { vv[e] = row[e]; ssum += vv[e]*vv[e]; }
        float inv = 1.0f / fmaxf(sqrtf(ssum), 1e-12f);
        #pragma unroll
        for (int e = 0; e < 16; e++) cn[t][e] = vv[e]*inv;
    }
    __syncthreads();

    // ---- knn top-2 (strict >, ties -> lower index; diag -2 never wins)
    if (t < SS) {
        float my[16];
        #pragma unroll
        for (int e = 0; e < 16; e++) my[e] = cn[t][e];
        float v1 = -3.f, v2 = -3.f; int i1 = -1, i2 = -1;
        for (int j = 0; j < SS; j++) {
            if (j == t) continue;
            float s = 0.f;
            #pragma unroll
            for (int e = 0; e < 16; e++) s = fmaf(my[e], cn[j][e], s);
            if (s > v1)      { v2 = v1; i2 = i1; v1 = s; i1 = j; }
            else if (s > v2) { v2 = s;  i2 = j; }
        }
        nbrs[t][0] = i1; nbrs[t][1] = i2;
    }
    if (t == 0) tot = 0;
    __syncthreads();

    // ---- directed edges + mutuality dedup (matches sort+uniq of reference)
    if (t < SS) {
        #pragma unroll
        for (int j = 0; j < 2; j++) {
            int p = nbrs[t][j];
            bool mutual = (nbrs[p][0] == t) || (nbrs[p][1] == t);
            unsigned char pv = (!mutual || (t < p)) ? 1 : 0;
            int q = (t*2 + j) * 2;
            edge[q]   = ((unsigned)p << 16) | (unsigned)t;   // p -> t
            edge[q+1] = ((unsigned)t << 16) | (unsigned)p;   // t -> p
            act[q] = pv; act[q+1] = pv;
        }
    }
    __syncthreads();

    // ---- fixpoint: keep edge iff in-deg(dst) > in-deg(src); stop on count unchanged
    int prev = -1;
    while (true) {
        if (t < SS) deg[t] = 0;
        __syncthreads();
        for (int e = t; e < EPB; e += 320)
            if (act[e]) atomicAdd(&deg[edge[e] & 0xFFFFu], 1u);
        __syncthreads();
        unsigned cnt = 0;
        for (int e = t; e < EPB; e += 320) {
            if (act[e]) {
                unsigned ed = edge[e];
                if (!(deg[ed & 0xFFFFu] > deg[ed >> 16])) act[e] = 0;
                cnt += act[e];
            }
        }
        for (int o = 32; o > 0; o >>= 1) cnt += __shfl_down(cnt, o, 64);
        if ((t & 63) == 0 && cnt) atomicAdd(&tot, cnt);
        __syncthreads();
        int total = (int)tot;
        __syncthreads();
        if (t == 0) tot = 0;
        if (total == prev) break;   // uniform
        prev = total;
    }

    // ---- out-degree -> nd = deg_src + 1
    if (t < SS) deg[t] = 0;
    __syncthreads();
    for (int e = t; e < EPB; e += 320)
        if (act[e]) atomicAdd(&deg[edge[e] >> 16], 1u);
    __syncthreads();
    if (t < SS) ndv[t] = (int)deg[t] + 1;
    __syncthreads();

    // ---- top-G by (deg desc, index asc) via rank counting
    if (t < SS) {
        int mine = ndv[t], rank = 0;
        for (int m = 0; m < SS; m++) {
            int v = ndv[m];
            rank += (v > mine) || (v == mine && m < t);
        }
        if (rank < GG) gsel[rank] = t;
    }
    if (t < SS) deg[t] = 0;   // reuse deg for in-degree (ndv already captured)
    __syncthreads();

    if (t < GG) {
        int n = gsel[t];
        selnode[b*GG + t] = n;
        selrow[b*GG + t]  = srow[n];
        out_attn[b*ATT + DENS + t] = ca_sorted[b*NNP + DENS + n];
    }
    if (t < DENS) out_attn[b*ATT + t] = ca_sorted[b*NNP + t];

    // ---- in-degree for CSR
    for (int e = t; e < EPB; e += 320)
        if (act[e]) atomicAdd(&deg[edge[e] & 0xFFFFu], 1u);
    __syncthreads();

    // ---- inclusive scan over 288 in-degrees (Hillis-Steele in LDS)
    unsigned dv = (t < SS) ? deg[t] : 0;
    scan[t] = dv;
    __syncthreads();
    for (int off = 1; off < SS; off <<= 1) {
        unsigned add = (t >= off) ? scan[t - off] : 0u;
        __syncthreads();
        scan[t] += add;
        __syncthreads();
    }
    if (t < SS) {
        rowptr[b*(SS+1) + t + 1] = scan[t];
        deg[t] = scan[t] - dv;   // cursor = exclusive prefix
    }
    if (t == 0) rowptr[b*(SS+1)] = 0;
    __syncthreads();

    // ---- scatter CSR columns as GLOBAL x row ids
    for (int e = t; e < EPB; e += 320) {
        if (act[e]) {
            unsigned ed = edge[e];
            unsigned pos = atomicAdd(&deg[ed & 0xFFFFu], 1u);
            col[b*EPB + pos] = (unsigned)srow[ed >> 16];
        }
    }
}

// ---------------------------------------------------------------- K3: tokens
__global__ __launch_bounds__(256) void k_tokens(const float* __restrict__ x,
                                                const int* __restrict__ order,
                                                const int* __restrict__ selnode,
                                                const int* __restrict__ selrow,
                                                const unsigned* __restrict__ rowptr,
                                                const unsigned* __restrict__ col,
                                                float* __restrict__ out) {
    const int wid  = threadIdx.x >> 6;
    const int lane = threadIdx.x & 63;
    int row = blockIdx.x*4 + wid;
    if (row >= BB*TOK) return;
    int b  = row / TOK;
    int tk = row - b*TOK;
    float4* __restrict__ orow = (float4*)(out + (size_t)row*DD);

    if (tk <= DENS) {
        int srcrow = (tk == 0) ? (b*NP1) : (b*NP1 + 1 + order[b*NNP + (tk-1)]);
        const float4* s4 = (const float4*)(x + (size_t)srcrow*DD);
        #pragma unroll
        for (int q = 0; q < 3; q++) orow[lane + q*64] = s4[lane + q*64];
    } else {
        int r = tk - 1 - DENS;
        int n = selnode[b*GG + r];
        int g = b*(SS+1) + n;
        unsigned e0 = rowptr[g], e1 = rowptr[g+1];
        float4 acc0 = make_float4(0,0,0,0), acc1 = acc0, acc2 = acc0;
        for (unsigned e = e0; e < e1; e++) {
            const float4* s4 = (const float4*)(x + (size_t)col[b*EPB + e]*DD);
            float4 a = s4[lane], bq = s4[lane + 64], c = s4[lane + 128];
            acc0.x += a.x;  acc0.y += a.y;  acc0.z += a.z;  acc0.w += a.w;
            acc1.x += bq.x; acc1.y += bq.y; acc1.z += bq.z; acc1.w += bq.w;
            acc2.x += c.x;  acc2.y += c.y;  acc2.z += c.z;  acc2.w += c.w;
        }
        const float4* s4 = (const float4*)(x + (size_t)selrow[b*GG + r]*DD);
        float4 a = s4[lane], bq = s4[lane + 64], c = s4[lane + 128];
        acc0.x += a.x;  acc0.y += a.y;  acc0.z += a.z;  acc0.w += a.w;
        acc1.x += bq.x; acc1.y += bq.y; acc1.z += bq.z; acc1.w += bq.w;
        acc2.x += c.x;  acc2.y += c.y;  acc2.z += c.z;  acc2.w += c.w;
        orow[lane]       = acc0;
        orow[lane + 64]  = acc1;
        orow[lane + 128] = acc2;
    }
}

// ---------------------------------------------------------------- launch
extern "C" void kernel_launch(void* const* d_in, const int* in_sizes, int n_in,
                              void* d_out, int out_size, void* d_ws, size_t ws_size,
                              hipStream_t stream) {
    const float* x  = (const float*)d_in[0];
    const float* ca = (const float*)d_in[1];
    const float* ex = (const float*)d_in[2];
    float* out = (float*)d_out;

    char* w = (char*)d_ws;
    int*      order     = (int*)w;      w += (size_t)BB*NNP*4;
    float*    ca_sorted = (float*)w;    w += (size_t)BB*NNP*4;
    unsigned* rowptr    = (unsigned*)w; w += (size_t)BB*(SS+1)*4;
    unsigned* col       = (unsigned*)w; w += (size_t)BB*EPB*4;
    int*      selnode   = (int*)w;      w += (size_t)BB*GG*4;
    int*      selrow    = (int*)w;      w += (size_t)BB*GG*4;

    float* out_attn = out + (size_t)BB*TOK*DD;

    k_sort<<<BB, 256, 0, stream>>>(ca, order, ca_sorted);
    k_graph<<<BB, 320, 0, stream>>>(ex, order, ca_sorted,
                                    rowptr, col, selnode, selrow, out_attn);
    k_tokens<<<(BB*TOK + 3)/4, 256, 0, stream>>>(x, order, selnode, selrow,
                                                 rowptr, col, out);
}

// Round 4
// 282.170 us; speedup vs baseline: 1.9314x; 1.0358x over previous
//
#include <hip/hip_runtime.h>
#include <hip/hip_bf16.h>
#include <math.h>

#define BB   64
#define NP1  577
#define DD   768
#define NNP  576      // N patches
#define DENS 288      // kept high-attn tokens
#define SS   288      // skip tokens (graph nodes per batch)
#define KNN  2
#define EPB  (SS*KNN*2)   // 1152 directed candidate edges per batch
#define GG   144
#define TOK  (1+DENS+GG)  // 433
#define ATT  (DENS+GG)    // 432
#define TPB  576          // threads per graph block (9 waves)

// ---------------------------------------------------------------- K1: fused graph
// per-batch, one block: rank-count sort -> knn -> pair dedup -> directional
// degree fixpoint -> out-degree top-G -> CSR (global x-row ids) -> attn out
__global__ __launch_bounds__(TPB) void k_graph(const float* __restrict__ ca,
                                               const float* __restrict__ ex,
                                               int* __restrict__ order_g,      // BB*NNP (only [0,DENS) used)
                                               unsigned* __restrict__ rowptr,  // BB*(SS+1)
                                               unsigned* __restrict__ col,     // BB*EPB
                                               int* __restrict__ selnode,      // BB*GG
                                               int* __restrict__ selrow,       // BB*GG
                                               float* __restrict__ out_attn) {
    __shared__ float    val[NNP];        // raw cls_attn
    __shared__ float    sortedv[NNP];    // sorted desc
    __shared__ short    sorder[NNP];     // orig index per rank
    __shared__ float    cn[SS][17];      // normalized expert features (+1 pad)
    __shared__ short    nbrs[SS][2];
    __shared__ unsigned edge[EPB];       // (src<<16)|dst, batch-local
    __shared__ unsigned char act[EPB];
    __shared__ unsigned deg[SS];
    __shared__ unsigned indeg[SS];       // final in-degree snapshot
    __shared__ int      ndv[SS];
    __shared__ unsigned scan[NNP];
    __shared__ int      srow[SS];        // global x row per node
    __shared__ short    gsel[GG];
    __shared__ int      changed;
    const int b = blockIdx.x, t = threadIdx.x;

    // ---- stable descending argsort via rank counting (no barriers in loop)
    float v = ca[b*NNP + t];
    val[t] = v;
    __syncthreads();
    int rank = 0;
    #pragma unroll 8
    for (int m = 0; m < NNP; m++) {
        float u = val[m];
        rank += (u > v) || (u == v && m < t);
    }
    sortedv[rank] = v;
    sorder[rank]  = (short)t;
    if (rank < DENS) order_g[b*NNP + rank] = t;   // kept-patch order for k_tokens
    __syncthreads();

    // attn head: nsca
    if (t < DENS) out_attn[b*ATT + t] = sortedv[t];

    // ---- load + normalize expert features of skip tokens
    if (t < SS) {
        int src = sorder[DENS + t];
        int row = b*NP1 + 1 + src;
        srow[t] = row;
        const float* rp = ex + (size_t)row * 16;
        float vv[16]; float ssum = 0.f;
        #pragma unroll
        for (int e = 0; e < 16; e++) { vv[e] = rp[e]; ssum += vv[e]*vv[e]; }
        float inv = 1.0f / fmaxf(sqrtf(ssum), 1e-12f);
        #pragma unroll
        for (int e = 0; e < 16; e++) cn[t][e] = vv[e]*inv;
    }
    __syncthreads();

    // ---- knn top-2 (strict >, ties -> lower index; diag never wins)
    if (t < SS) {
        float my[16];
        #pragma unroll
        for (int e = 0; e < 16; e++) my[e] = cn[t][e];
        float v1 = -3.f, v2 = -3.f; int i1 = -1, i2 = -1;
        for (int j = 0; j < SS; j++) {
            if (j == t) continue;
            float s = 0.f;
            #pragma unroll
            for (int e = 0; e < 16; e++) s = fmaf(my[e], cn[j][e], s);
            if (s > v1)      { v2 = v1; i2 = i1; v1 = s; i1 = j; }
            else if (s > v2) { v2 = s;  i2 = j; }
        }
        nbrs[t][0] = (short)i1; nbrs[t][1] = (short)i2;
    }
    __syncthreads();

    // ---- directed edges + mutuality dedup (== sort+uniq of reference)
    if (t < SS) {
        #pragma unroll
        for (int j = 0; j < 2; j++) {
            int p = nbrs[t][j];
            bool mutual = (nbrs[p][0] == t) || (nbrs[p][1] == t);
            unsigned char pv = (!mutual || (t < p)) ? 1 : 0;
            int q = (t*2 + j) * 2;
            edge[q]   = ((unsigned)p << 16) | (unsigned)t;   // p -> t
            edge[q+1] = ((unsigned)t << 16) | (unsigned)p;   // t -> p
            act[q] = pv; act[q+1] = pv;
        }
    }
    __syncthreads();

    // ---- fixpoint: keep edge iff indeg(dst) > indeg(src); stop when no removal
    while (true) {
        if (t < SS) deg[t] = 0;
        if (t == 0) changed = 0;
        __syncthreads();
        #pragma unroll
        for (int e = t; e < EPB; e += TPB)
            if (act[e]) atomicAdd(&deg[edge[e] & 0xFFFFu], 1u);
        __syncthreads();
        #pragma unroll
        for (int e = t; e < EPB; e += TPB) {
            if (act[e]) {
                unsigned ed = edge[e];
                if (!(deg[ed & 0xFFFFu] > deg[ed >> 16])) { act[e] = 0; changed = 1; }
            }
        }
        __syncthreads();
        int ch = changed;
        __syncthreads();           // protects next iteration's re-zero
        if (!ch) break;
    }
    // deg[] now holds the FINAL in-degree (last iteration removed nothing)
    if (t < SS) indeg[t] = deg[t];
    __syncthreads();

    // ---- out-degree -> nd = deg_src + 1
    if (t < SS) deg[t] = 0;
    __syncthreads();
    #pragma unroll
    for (int e = t; e < EPB; e += TPB)
        if (act[e]) atomicAdd(&deg[edge[e] >> 16], 1u);
    __syncthreads();
    if (t < SS) ndv[t] = (int)deg[t] + 1;
    __syncthreads();

    // ---- top-G by (deg desc, index asc) via rank counting
    if (t < SS) {
        int mine = ndv[t], r = 0;
        for (int m = 0; m < SS; m++) {
            int u = ndv[m];
            r += (u > mine) || (u == mine && m < t);
        }
        if (r < GG) gsel[r] = (short)t;
    }
    __syncthreads();

    if (t < GG) {
        int n = gsel[t];
        selnode[b*GG + t] = n;
        selrow[b*GG + t]  = srow[n];
        out_attn[b*ATT + DENS + t] = sortedv[DENS + n];
    }

    // ---- exclusive scan of final in-degrees -> rowptr + cursors
    unsigned dv = (t < SS) ? indeg[t] : 0u;
    scan[t] = dv;
    __syncthreads();
    for (int off = 1; off < SS; off <<= 1) {
        unsigned add = (t >= off) ? scan[t - off] : 0u;
        __syncthreads();
        scan[t] += add;
        __syncthreads();
    }
    if (t < SS) {
        rowptr[b*(SS+1) + t + 1] = scan[t];
        deg[t] = scan[t] - dv;    // cursor = exclusive prefix (reuse deg)
    }
    if (t == 0) rowptr[b*(SS+1)] = 0;
    __syncthreads();

    // ---- scatter CSR columns as GLOBAL x row ids
    #pragma unroll
    for (int e = t; e < EPB; e += TPB) {
        if (act[e]) {
            unsigned ed = edge[e];
            unsigned pos = atomicAdd(&deg[ed & 0xFFFFu], 1u);
            col[b*EPB + pos] = (unsigned)srow[ed >> 16];
        }
    }
}

// ---------------------------------------------------------------- K2: tokens
__global__ __launch_bounds__(256) void k_tokens(const float* __restrict__ x,
                                                const int* __restrict__ order,
                                                const int* __restrict__ selnode,
                                                const int* __restrict__ selrow,
                                                const unsigned* __restrict__ rowptr,
                                                const unsigned* __restrict__ col,
                                                float* __restrict__ out) {
    const int wid  = threadIdx.x >> 6;
    const int lane = threadIdx.x & 63;
    int row = blockIdx.x*4 + wid;
    if (row >= BB*TOK) return;
    int b  = row / TOK;
    int tk = row - b*TOK;
    float4* __restrict__ orow = (float4*)(out + (size_t)row*DD);

    if (tk <= DENS) {
        int srcrow = (tk == 0) ? (b*NP1) : (b*NP1 + 1 + order[b*NNP + (tk-1)]);
        const float4* s4 = (const float4*)(x + (size_t)srcrow*DD);
        #pragma unroll
        for (int q = 0; q < 3; q++) orow[lane + q*64] = s4[lane + q*64];
    } else {
        int r = tk - 1 - DENS;
        int n = selnode[b*GG + r];
        int g = b*(SS+1) + n;
        unsigned e0 = rowptr[g], e1 = rowptr[g+1];
        float4 acc0 = make_float4(0,0,0,0), acc1 = acc0, acc2 = acc0;
        for (unsigned e = e0; e < e1; e++) {
            const float4* s4 = (const float4*)(x + (size_t)col[b*EPB + e]*DD);
            float4 a = s4[lane], bq = s4[lane + 64], c = s4[lane + 128];
            acc0.x += a.x;  acc0.y += a.y;  acc0.z += a.z;  acc0.w += a.w;
            acc1.x += bq.x; acc1.y += bq.y; acc1.z += bq.z; acc1.w += bq.w;
            acc2.x += c.x;  acc2.y += c.y;  acc2.z += c.z;  acc2.w += c.w;
        }
        const float4* s4 = (const float4*)(x + (size_t)selrow[b*GG + r]*DD);
        float4 a = s4[lane], bq = s4[lane + 64], c = s4[lane + 128];
        acc0.x += a.x;  acc0.y += a.y;  acc0.z += a.z;  acc0.w += a.w;
        acc1.x += bq.x; acc1.y += bq.y; acc1.z += bq.z; acc1.w += bq.w;
        acc2.x += c.x;  acc2.y += c.y;  acc2.z += c.z;  acc2.w += c.w;
        orow[lane]       = acc0;
        orow[lane + 64]  = acc1;
        orow[lane + 128] = acc2;
    }
}

// ---------------------------------------------------------------- launch
extern "C" void kernel_launch(void* const* d_in, const int* in_sizes, int n_in,
                              void* d_out, int out_size, void* d_ws, size_t ws_size,
                              hipStream_t stream) {
    const float* x  = (const float*)d_in[0];
    const float* ca = (const float*)d_in[1];
    const float* ex = (const float*)d_in[2];
    float* out = (float*)d_out;

    char* w = (char*)d_ws;
    int*      order   = (int*)w;      w += (size_t)BB*NNP*4;
    unsigned* rowptr  = (unsigned*)w; w += (size_t)BB*(SS+1)*4;
    unsigned* col     = (unsigned*)w; w += (size_t)BB*EPB*4;
    int*      selnode = (int*)w;      w += (size_t)BB*GG*4;
    int*      selrow  = (int*)w;      w += (size_t)BB*GG*4;

    float* out_attn = out + (size_t)BB*TOK*DD;

    k_graph<<<BB, TPB, 0, stream>>>(ca, ex, order, rowptr, col,
                                    selnode, selrow, out_attn);
    k_tokens<<<(BB*TOK + 3)/4, 256, 0, stream>>>(x, order, selnode, selrow,
                                                 rowptr, col, out);
}

// Round 6
// 247.609 us; speedup vs baseline: 2.2010x; 1.1396x over previous
//
#include <hip/hip_runtime.h>
#include <hip/hip_bf16.h>
#include <math.h>

#define BB   64
#define NP1  577
#define DD   768
#define NNP  576      // N patches
#define DENS 288      // kept high-attn tokens
#define SS   288      // skip tokens (graph nodes per batch)
#define KNN  2
#define EPB  (SS*KNN*2)   // 1152 directed candidate edges per batch
#define GG   144
#define TOK  (1+DENS+GG)  // 433
#define ATT  (DENS+GG)    // 432
#define TPB  576          // threads per graph block (9 waves)
#define HALF 144          // j-range per half in kNN

// ---------------------------------------------------------------- K1: fused graph
__global__ __launch_bounds__(TPB) void k_graph(const float* __restrict__ ca,
                                               const float* __restrict__ ex,
                                               int* __restrict__ order_g,      // BB*NNP (only [0,DENS))
                                               unsigned* __restrict__ rowptr,  // BB*(SS+1)
                                               unsigned* __restrict__ col,     // BB*EPB
                                               int* __restrict__ selnode,      // BB*GG
                                               int* __restrict__ selrow,       // BB*GG
                                               float* __restrict__ out_attn) {
    __shared__ __align__(16) float val[NNP];
    __shared__ float    sortedv[NNP];
    __shared__ short    sorder[NNP];
    __shared__ float4   cn4[SS][4];      // normalized expert features
    __shared__ short    nbrs[SS][2];
    __shared__ unsigned edge[EPB];       // (src<<16)|dst, batch-local
    __shared__ unsigned char act[EPB];
    __shared__ unsigned deg[SS];
    __shared__ unsigned indeg[SS];
    __shared__ __align__(16) int ndv[SS];
    __shared__ unsigned scan[NNP];
    __shared__ int      srow[SS];
    __shared__ short    gsel[GG];
    __shared__ float    cval[2][SS][2];  // kNN half-candidates
    __shared__ short    cidx[2][SS][2];
    __shared__ short    rankp[2][SS];
    const int b = blockIdx.x, t = threadIdx.x;
    const int h  = (t >= SS) ? 1 : 0;    // half id
    const int n  = t - h*SS;             // node id within half

    // ---- stable descending argsort via rank counting (vectorized reads)
    float v = ca[b*NNP + t];
    val[t] = v;
    __syncthreads();
    {
        const float4* v4 = (const float4*)val;
        int rank = 0;
        #pragma unroll 4
        for (int m4 = 0; m4 < NNP/4; m4++) {
            float4 u = v4[m4];
            int m = m4*4;
            rank += (u.x > v) || (u.x == v && m   < t);
            rank += (u.y > v) || (u.y == v && m+1 < t);
            rank += (u.z > v) || (u.z == v && m+2 < t);
            rank += (u.w > v) || (u.w == v && m+3 < t);
        }
        sortedv[rank] = v;
        sorder[rank]  = (short)t;
        if (rank < DENS) order_g[b*NNP + rank] = t;
    }
    __syncthreads();

    if (t < DENS) out_attn[b*ATT + t] = sortedv[t];

    // ---- load + normalize expert features (float4)
    if (t < SS) {
        int src = sorder[DENS + t];
        int row = b*NP1 + 1 + src;
        srow[t] = row;
        const float4* rp = (const float4*)(ex + (size_t)row * 16);
        float4 f0 = rp[0], f1 = rp[1], f2 = rp[2], f3 = rp[3];
        float ssum = f0.x*f0.x + f0.y*f0.y + f0.z*f0.z + f0.w*f0.w
                   + f1.x*f1.x + f1.y*f1.y + f1.z*f1.z + f1.w*f1.w
                   + f2.x*f2.x + f2.y*f2.y + f2.z*f2.z + f2.w*f2.w
                   + f3.x*f3.x + f3.y*f3.y + f3.z*f3.z + f3.w*f3.w;
        float inv = 1.0f / fmaxf(sqrtf(ssum), 1e-12f);
        f0.x*=inv; f0.y*=inv; f0.z*=inv; f0.w*=inv;
        f1.x*=inv; f1.y*=inv; f1.z*=inv; f1.w*=inv;
        f2.x*=inv; f2.y*=inv; f2.z*=inv; f2.w*=inv;
        f3.x*=inv; f3.y*=inv; f3.z*=inv; f3.w*=inv;
        cn4[t][0]=f0; cn4[t][1]=f1; cn4[t][2]=f2; cn4[t][3]=f3;
    }
    __syncthreads();

    // ---- kNN top-2: 2 threads/node, each scans one index half, 4-way unroll
    {
        const float4 m0 = cn4[n][0], m1 = cn4[n][1], m2 = cn4[n][2], m3 = cn4[n][3];
        float v1 = -3.f, v2 = -3.f; int i1 = -1, i2 = -1;
        const int jbeg = h*HALF;
        #pragma unroll 2
        for (int j = jbeg; j < jbeg + HALF; j += 4) {
            float sq[4];
            #pragma unroll
            for (int q = 0; q < 4; q++) {
                const float4 a0 = cn4[j+q][0], a1 = cn4[j+q][1],
                             a2 = cn4[j+q][2], a3 = cn4[j+q][3];
                float s = m0.x*a0.x;
                s = fmaf(m0.y,a0.y,s); s = fmaf(m0.z,a0.z,s); s = fmaf(m0.w,a0.w,s);
                s = fmaf(m1.x,a1.x,s); s = fmaf(m1.y,a1.y,s); s = fmaf(m1.z,a1.z,s); s = fmaf(m1.w,a1.w,s);
                s = fmaf(m2.x,a2.x,s); s = fmaf(m2.y,a2.y,s); s = fmaf(m2.z,a2.z,s); s = fmaf(m2.w,a2.w,s);
                s = fmaf(m3.x,a3.x,s); s = fmaf(m3.y,a3.y,s); s = fmaf(m3.z,a3.z,s); s = fmaf(m3.w,a3.w,s);
                sq[q] = (j+q == n) ? -3.f : s;
            }
            #pragma unroll
            for (int q = 0; q < 4; q++) {
                if (sq[q] > v1)      { v2 = v1; i2 = i1; v1 = sq[q]; i1 = j+q; }
                else if (sq[q] > v2) { v2 = sq[q]; i2 = j+q; }
            }
        }
        cval[h][n][0] = v1; cval[h][n][1] = v2;
        cidx[h][n][0] = (short)i1; cidx[h][n][1] = (short)i2;
    }
    __syncthreads();

    // merge halves (all low-half indices < high-half indices; ties -> low half)
    if (t < SS) {
        float a1 = cval[0][t][0], a2 = cval[0][t][1];
        float b1 = cval[1][t][0], b2 = cval[1][t][1];
        short ia1 = cidx[0][t][0], ia2 = cidx[0][t][1];
        short ib1 = cidx[1][t][0], ib2 = cidx[1][t][1];
        short j1, j2;
        if (b1 > a1) { j1 = ib1; j2 = (b2 > a1) ? ib2 : ia1; }
        else         { j1 = ia1; j2 = (b1 > a2) ? ib1 : ia2; }
        nbrs[t][0] = j1; nbrs[t][1] = j2;
    }
    __syncthreads();

    // ---- directed edges + mutuality dedup (== sort+uniq of reference)
    if (t < SS) {
        #pragma unroll
        for (int j = 0; j < 2; j++) {
            int p = nbrs[t][j];
            bool mutual = (nbrs[p][0] == t) || (nbrs[p][1] == t);
            unsigned char pv = (!mutual || (t < p)) ? 1 : 0;
            int q = (t*2 + j) * 2;
            edge[q]   = ((unsigned)p << 16) | (unsigned)t;   // p -> t
            edge[q+1] = ((unsigned)t << 16) | (unsigned)p;   // t -> p
            act[q] = pv; act[q+1] = pv;
        }
    }
    __syncthreads();

    // ---- fixpoint: keep edge iff indeg(dst) > indeg(src); 3 barriers/iter
    for (;;) {
        if (t < SS) deg[t] = 0;
        __syncthreads();
        #pragma unroll
        for (int e = t; e < EPB; e += TPB)
            if (act[e]) atomicAdd(&deg[edge[e] & 0xFFFFu], 1u);
        __syncthreads();
        int removed = 0;
        #pragma unroll
        for (int e = t; e < EPB; e += TPB) {
            if (act[e]) {
                unsigned ed = edge[e];
                if (!(deg[ed & 0xFFFFu] > deg[ed >> 16])) { act[e] = 0; removed = 1; }
            }
        }
        if (__syncthreads_count(removed) == 0) break;
    }
    // deg[] == final in-degree (last pass removed nothing)
    if (t < SS) indeg[t] = deg[t];
    __syncthreads();

    // ---- out-degree -> nd = deg_src + 1
    if (t < SS) deg[t] = 0;
    __syncthreads();
    #pragma unroll
    for (int e = t; e < EPB; e += TPB)
        if (act[e]) atomicAdd(&deg[edge[e] >> 16], 1u);
    __syncthreads();
    if (t < SS) ndv[t] = (int)deg[t] + 1;
    __syncthreads();

    // ---- top-G by (deg desc, index asc): 2 threads/node partial rank counts
    {
        const int4* nd4 = (const int4*)ndv;
        int mine = ndv[n];
        int r = 0;
        const int m4beg = h*(HALF/4);
        #pragma unroll 4
        for (int m4 = m4beg; m4 < m4beg + HALF/4; m4++) {
            int4 u = nd4[m4];
            int m = m4*4;
            r += (u.x > mine) || (u.x == mine && m   < n);
            r += (u.y > mine) || (u.y == mine && m+1 < n);
            r += (u.z > mine) || (u.z == mine && m+2 < n);
            r += (u.w > mine) || (u.w == mine && m+3 < n);
        }
        rankp[h][n] = (short)r;
    }
    __syncthreads();
    if (t < SS) {
        int r = (int)rankp[0][t] + (int)rankp[1][t];
        if (r < GG) gsel[r] = (short)t;
    }
    __syncthreads();

    if (t < GG) {
        int nn = gsel[t];
        selnode[b*GG + t] = nn;
        selrow[b*GG + t]  = srow[nn];
        out_attn[b*ATT + DENS + t] = sortedv[DENS + nn];
    }

    // ---- exclusive scan of final in-degrees -> rowptr + cursors
    unsigned dv = (t < SS) ? indeg[t] : 0u;
    scan[t] = dv;
    __syncthreads();
    for (int off = 1; off < SS; off <<= 1) {
        unsigned add = (t >= off) ? scan[t - off] : 0u;
        __syncthreads();
        scan[t] += add;
        __syncthreads();
    }
    if (t < SS) {
        rowptr[b*(SS+1) + t + 1] = scan[t];
        deg[t] = scan[t] - dv;    // cursor = exclusive prefix (reuse deg)
    }
    if (t == 0) rowptr[b*(SS+1)] = 0;
    __syncthreads();

    // ---- scatter CSR columns as GLOBAL x row ids
    #pragma unroll
    for (int e = t; e < EPB; e += TPB) {
        if (act[e]) {
            unsigned ed = edge[e];
            unsigned pos = atomicAdd(&deg[ed & 0xFFFFu], 1u);
            col[b*EPB + pos] = (unsigned)srow[ed >> 16];
        }
    }
}

// ---------------------------------------------------------------- K2: tokens
__global__ __launch_bounds__(256) void k_tokens(const float* __restrict__ x,
                                                const int* __restrict__ order,
                                                const int* __restrict__ selnode,
                                                const int* __restrict__ selrow,
                                                const unsigned* __restrict__ rowptr,
                                                const unsigned* __restrict__ col,
                                                float* __restrict__ out) {
    const int wid  = threadIdx.x >> 6;
    const int lane = threadIdx.x & 63;
    int row = blockIdx.x*4 + wid;
    if (row >= BB*TOK) return;
    int b  = row / TOK;
    int tk = row - b*TOK;
    float4* __restrict__ orow = (float4*)(out + (size_t)row*DD);

    if (tk <= DENS) {
        int srcrow = (tk == 0) ? (b*NP1) : (b*NP1 + 1 + order[b*NNP + (tk-1)]);
        const float4* s4 = (const float4*)(x + (size_t)srcrow*DD);
        #pragma unroll
        for (int q = 0; q < 3; q++) orow[lane + q*64] = s4[lane + q*64];
    } else {
        int r = tk - 1 - DENS;
        int n = selnode[b*GG + r];
        int g = b*(SS+1) + n;
        unsigned e0 = rowptr[g], e1 = rowptr[g+1];
        float4 acc0 = make_float4(0,0,0,0), acc1 = acc0, acc2 = acc0;
        for (unsigned e = e0; e < e1; e++) {
            const float4* s4 = (const float4*)(x + (size_t)col[b*EPB + e]*DD);
            float4 a = s4[lane], bq = s4[lane + 64], c = s4[lane + 128];
            acc0.x += a.x;  acc0.y += a.y;  acc0.z += a.z;  acc0.w += a.w;
            acc1.x += bq.x; acc1.y += bq.y; acc1.z += bq.z; acc1.w += bq.w;
            acc2.x += c.x;  acc2.y += c.y;  acc2.z += c.z;  acc2.w += c.w;
        }
        const float4* s4 = (const float4*)(x + (size_t)selrow[b*GG + r]*DD);
        float4 a = s4[lane], bq = s4[lane + 64], c = s4[lane + 128];
        acc0.x += a.x;  acc0.y += a.y;  acc0.z += a.z;  acc0.w += a.w;
        acc1.x += bq.x; acc1.y += bq.y; acc1.z += bq.z; acc1.w += bq.w;
        acc2.x += c.x;  acc2.y += c.y;  acc2.z += c.z;  acc2.w += c.w;
        orow[lane]       = acc0;
        orow[lane + 64]  = acc1;
        orow[lane + 128] = acc2;
    }
}

// ---------------------------------------------------------------- launch
extern "C" void kernel_launch(void* const* d_in, const int* in_sizes, int n_in,
                              void* d_out, int out_size, void* d_ws, size_t ws_size,
                              hipStream_t stream) {
    const float* x  = (const float*)d_in[0];
    const float* ca = (const float*)d_in[1];
    const float* ex = (const float*)d_in[2];
    float* out = (float*)d_out;

    char* w = (char*)d_ws;
    int*      order   = (int*)w;      w += (size_t)BB*NNP*4;
    unsigned* rowptr  = (unsigned*)w; w += (size_t)BB*(SS+1)*4;
    unsigned* col     = (unsigned*)w; w += (size_t)BB*EPB*4;
    int*      selnode = (int*)w;      w += (size_t)BB*GG*4;
    int*      selrow  = (int*)w;      w += (size_t)BB*GG*4;

    float* out_attn = out + (size_t)BB*TOK*DD;

    k_graph<<<BB, TPB, 0, stream>>>(ca, ex, order, rowptr, col,
                                    selnode, selrow, out_attn);
    k_tokens<<<(BB*TOK + 3)/4, 256, 0, stream>>>(x, order, selnode, selrow,
                                                 rowptr, col, out);
}